// Round 3
// baseline (2340.666 us; speedup 1.0000x reference)
//
#include <hip/hip_runtime.h>
#include <hip/hip_bf16.h>
#include <math.h>

// Problem constants
#define NB       128
#define P_HW     196
#define ENC_C    2048
#define V_SZ     10000
#define E_SZ     512
#define D_SZ     512
#define MAXLEN   32
#define T_STEPS  31

// d_out layout (floats), in reference return order
#define SZ_PRED    (128ULL * 31ULL * 10000ULL)
#define OFF_PRED   0ULL
#define OFF_CAPT   (SZ_PRED)
#define OFF_DECLEN (OFF_CAPT + 128ULL * 32ULL)
#define OFF_ALPHA  (OFF_DECLEN + 128ULL)
#define OFF_SORT   (OFF_ALPHA + 128ULL * 31ULL * 196ULL)

typedef __bf16 bf16x8 __attribute__((ext_vector_type(8)));
typedef float f32x4 __attribute__((ext_vector_type(4)));

__device__ __forceinline__ float sigf(float x) { return 1.0f / (1.0f + __expf(-x)); }

__device__ __forceinline__ unsigned short f2bf(float f) {
    unsigned int u = __float_as_uint(f);
    unsigned int r = (u + 0x7fffu + ((u >> 16) & 1u)) >> 16;  // RNE
    return (unsigned short)r;
}

// ---------------------------------------------------------------------------
// Stable descending sort by caption length (rank via O(N^2) count)
// ---------------------------------------------------------------------------
__global__ void sort_kernel(const int* __restrict__ capt_lengths,
                            const int* __restrict__ enc_capt,
                            int* __restrict__ sort_ind_ws,
                            int* __restrict__ dec_len_ws,
                            int* __restrict__ capt_sorted_ws,
                            float* __restrict__ dout) {
    __shared__ int cl[NB];
    int i = threadIdx.x;
    cl[i] = capt_lengths[i];
    __syncthreads();
    int my = cl[i];
    int rank = 0;
    #pragma unroll 4
    for (int j = 0; j < NB; ++j) {
        int cj = cl[j];
        rank += (cj > my) || (cj == my && j < i);
    }
    sort_ind_ws[rank] = i;
    dec_len_ws[rank]  = my - 1;
    dout[OFF_SORT + rank]   = (float)i;
    dout[OFF_DECLEN + rank] = (float)(my - 1);
    for (int t = 0; t < MAXLEN; ++t) {
        int tok = enc_capt[i * MAXLEN + t];
        capt_sorted_ws[rank * MAXLEN + t] = tok;
        dout[OFF_CAPT + rank * MAXLEN + t] = (float)tok;
    }
}

// ---------------------------------------------------------------------------
// mean_feat[b, e] = mean over 196 positions; writes fp32 + bf16 copies
// ---------------------------------------------------------------------------
__global__ void mean_kernel(const float* __restrict__ enc_feature,
                            const int* __restrict__ sort_ind,
                            float* __restrict__ mean_feat,
                            unsigned short* __restrict__ mean16) {
    int b = blockIdx.y;
    int e = blockIdx.x * 256 + threadIdx.x;
    int src = sort_ind[b];
    const float* base = enc_feature + (size_t)src * P_HW * ENC_C + e;
    float s = 0.0f;
    #pragma unroll 4
    for (int p = 0; p < P_HW; ++p) s += base[(size_t)p * ENC_C];
    float m = s * (1.0f / (float)P_HW);
    mean_feat[(size_t)b * ENC_C + e] = m;
    mean16[(size_t)b * ENC_C + e] = f2bf(m);
}

// ---------------------------------------------------------------------------
__global__ void f32_to_bf16(const float* __restrict__ src,
                            unsigned short* __restrict__ dst, int n) {
    int i = (blockIdx.x * 256 + threadIdx.x) * 4;
    if (i < n) {
        float4 v = *reinterpret_cast<const float4*>(src + i);
        dst[i + 0] = f2bf(v.x);
        dst[i + 1] = f2bf(v.y);
        dst[i + 2] = f2bf(v.z);
        dst[i + 3] = f2bf(v.w);
    }
}

// Wg16[n][0:2560] = W_ih[n], Wg16[n][2560:3072] = W_hh[n]
__global__ void concat_wg(const float* __restrict__ W_ih,
                          const float* __restrict__ W_hh,
                          unsigned short* __restrict__ Wg16) {
    int n = blockIdx.y;
    int col = blockIdx.x * 256 + threadIdx.x;  // < 3072
    float v = (col < 2560) ? W_ih[(size_t)n * 2560 + col]
                           : W_hh[(size_t)n * 512 + (col - 2560)];
    Wg16[(size_t)n * 3072 + col] = f2bf(v);
}

__global__ void bsum_kernel(const float* __restrict__ b_ih,
                            const float* __restrict__ b_hh,
                            float* __restrict__ bsum) {
    int i = blockIdx.x * 256 + threadIdx.x;  // 2048
    bsum[i] = b_ih[i] + b_hh[i];
}

// embs16[t][b][e] = bf16(emb[capt_sorted[b][t]][e])
__global__ void embs_gather(const float* __restrict__ emb,
                            const int* __restrict__ capt_sorted,
                            unsigned short* __restrict__ embs16) {
    int idx = blockIdx.x * 256 + threadIdx.x;  // 31*128*512
    if (idx >= 31 * 128 * 512) return;
    int t = idx >> 16;
    int r = idx & 65535;
    int b = r >> 9;
    int tok = capt_sorted[b * MAXLEN + t];
    embs16[idx] = f2bf(emb[(size_t)tok * E_SZ + (r & 511)]);
}

// ---------------------------------------------------------------------------
// LDS-free 1-wave MFMA GEMM (used only for the two init GEMMs).
// EPI 0: Cf = acc + bias ; EPI 4: Cb = bf16(acc + bias)
// ---------------------------------------------------------------------------
template <int EPI>
__global__ __launch_bounds__(64) void mfma_gemm(
    const unsigned short* __restrict__ A, int lda,
    const unsigned short* __restrict__ B, int ldb,
    int Nout, int K,
    const float* __restrict__ bias,
    float* __restrict__ Cf, unsigned short* __restrict__ Cb, int ldc) {
    int l = threadIdx.x;
    int lm = l & 15;
    int lk = (l >> 4) << 3;
    int row0 = blockIdx.y << 5;
    int col0 = blockIdx.x << 5;
    const unsigned short* pa0 = A + (size_t)(row0 + lm) * lda + lk;
    const unsigned short* pa1 = pa0 + ((size_t)lda << 4);
    const unsigned short* pb0 = B + (size_t)(col0 + lm) * ldb + lk;
    const unsigned short* pb1 = pb0 + ((size_t)ldb << 4);
    f32x4 acc00 = {0.f, 0.f, 0.f, 0.f}, acc01 = acc00, acc10 = acc00, acc11 = acc00;
    for (int k = 0; k < K; k += 32) {
        bf16x8 a0 = *(const bf16x8*)(pa0 + k);
        bf16x8 a1 = *(const bf16x8*)(pa1 + k);
        bf16x8 b0 = *(const bf16x8*)(pb0 + k);
        bf16x8 b1 = *(const bf16x8*)(pb1 + k);
        acc00 = __builtin_amdgcn_mfma_f32_16x16x32_bf16(a0, b0, acc00, 0, 0, 0);
        acc01 = __builtin_amdgcn_mfma_f32_16x16x32_bf16(a0, b1, acc01, 0, 0, 0);
        acc10 = __builtin_amdgcn_mfma_f32_16x16x32_bf16(a1, b0, acc10, 0, 0, 0);
        acc11 = __builtin_amdgcn_mfma_f32_16x16x32_bf16(a1, b1, acc11, 0, 0, 0);
    }
    int orow = (l >> 4) << 2;
    #pragma unroll
    for (int mi = 0; mi < 2; ++mi) {
        #pragma unroll
        for (int ni = 0; ni < 2; ++ni) {
            f32x4 v = (mi == 0) ? (ni == 0 ? acc00 : acc01)
                                : (ni == 0 ? acc10 : acc11);
            int col = col0 + ni * 16 + lm;
            #pragma unroll
            for (int r = 0; r < 4; ++r) {
                int row = row0 + mi * 16 + orow + r;
                float val = v[r] + bias[col];
                if (EPI == 0) Cf[(size_t)row * ldc + col] = val;
                else          Cb[(size_t)row * ldc + col] = f2bf(val);
            }
        }
    }
}

// ---------------------------------------------------------------------------
// awe = bf16(mean * sigmoid(h @ Wfb^T + b)), 4 waves: 2 col-tiles x K-split-2
// grid (32, 4), 256 threads. Block: 32 rows x 64 cols.
// ---------------------------------------------------------------------------
__global__ __launch_bounds__(256) void awe_fused(
    const unsigned short* __restrict__ h16,
    const unsigned short* __restrict__ Wfb,
    const float* __restrict__ b_fbeta,
    const float* __restrict__ meanfeat,
    unsigned short* __restrict__ awe16) {
    __shared__ float red[2][1024];
    int tid = threadIdx.x;
    int w = tid >> 6, l = tid & 63;
    int ct = w >> 1, ks = w & 1;
    int lm = l & 15, lk = ((l >> 4) << 3);
    int row0 = blockIdx.y << 5;
    int col0 = (blockIdx.x << 6) + (ct << 5);
    int kbase = ks << 8;  // 0 or 256
    const unsigned short* pa0 = h16 + (size_t)(row0 + lm) * 512 + kbase + lk;
    const unsigned short* pa1 = pa0 + 16 * 512;
    const unsigned short* pb0 = Wfb + (size_t)(col0 + lm) * 512 + kbase + lk;
    const unsigned short* pb1 = pb0 + 16 * 512;
    f32x4 acc00 = {0.f, 0.f, 0.f, 0.f}, acc01 = acc00, acc10 = acc00, acc11 = acc00;
    #pragma unroll
    for (int k = 0; k < 256; k += 32) {
        bf16x8 a0 = *(const bf16x8*)(pa0 + k);
        bf16x8 a1 = *(const bf16x8*)(pa1 + k);
        bf16x8 b0 = *(const bf16x8*)(pb0 + k);
        bf16x8 b1 = *(const bf16x8*)(pb1 + k);
        acc00 = __builtin_amdgcn_mfma_f32_16x16x32_bf16(a0, b0, acc00, 0, 0, 0);
        acc01 = __builtin_amdgcn_mfma_f32_16x16x32_bf16(a0, b1, acc01, 0, 0, 0);
        acc10 = __builtin_amdgcn_mfma_f32_16x16x32_bf16(a1, b0, acc10, 0, 0, 0);
        acc11 = __builtin_amdgcn_mfma_f32_16x16x32_bf16(a1, b1, acc11, 0, 0, 0);
    }
    int orow = (l >> 4) << 2;
    if (ks == 1) {
        #pragma unroll
        for (int mi = 0; mi < 2; ++mi)
            #pragma unroll
            for (int ni = 0; ni < 2; ++ni) {
                f32x4 v = (mi == 0) ? (ni == 0 ? acc00 : acc01)
                                    : (ni == 0 ? acc10 : acc11);
                #pragma unroll
                for (int r = 0; r < 4; ++r)
                    red[ct][(mi * 16 + orow + r) * 32 + ni * 16 + lm] = v[r];
            }
    }
    __syncthreads();
    if (ks == 0) {
        #pragma unroll
        for (int mi = 0; mi < 2; ++mi)
            #pragma unroll
            for (int ni = 0; ni < 2; ++ni) {
                f32x4 v = (mi == 0) ? (ni == 0 ? acc00 : acc01)
                                    : (ni == 0 ? acc10 : acc11);
                int col = col0 + ni * 16 + lm;
                #pragma unroll
                for (int r = 0; r < 4; ++r) {
                    int row = row0 + mi * 16 + orow + r;
                    float val = v[r] + red[ct][(mi * 16 + orow + r) * 32 + ni * 16 + lm]
                              + b_fbeta[col];
                    awe16[(size_t)row * 2048 + col] =
                        f2bf(meanfeat[(size_t)row * 2048 + col] * sigf(val));
                }
            }
    }
}

// ---------------------------------------------------------------------------
// Fused LSTM gate GEMM + pointwise. Block: 32 rows x 32 d-values, all 4 gates.
// 16 waves = 4 gates x K-split-4 (768 each). grid (16, 4), 1024 threads.
// ---------------------------------------------------------------------------
__global__ __launch_bounds__(1024) void lstm_fused(
    const unsigned short* __restrict__ embt,
    const unsigned short* __restrict__ awe16,
    const unsigned short* __restrict__ h16,
    const unsigned short* __restrict__ Wg,
    const float* __restrict__ bsum,
    float* __restrict__ c,
    unsigned short* __restrict__ h16out,
    unsigned short* __restrict__ hnew16,   // = hnew_all + t*65536
    const int* __restrict__ dec_len, int t) {
    __shared__ float red[12][1024];
    __shared__ float gates[4][1024];
    int tid = threadIdx.x;
    int w = tid >> 6, l = tid & 63;
    int g = w & 3, ks = w >> 2;
    int lm = l & 15, lk = ((l >> 4) << 3);
    int row0 = blockIdx.y << 5;
    int d0 = blockIdx.x << 5;
    int r0 = row0 + lm;
    const unsigned short* pe0 = embt + (size_t)r0 * 512 + lk;
    const unsigned short* pe1 = pe0 + 16 * 512;
    const unsigned short* pw0 = awe16 + (size_t)r0 * 2048 + lk;
    const unsigned short* pw1 = pw0 + 16 * 2048;
    const unsigned short* ph0 = h16 + (size_t)r0 * 512 + lk;
    const unsigned short* ph1 = ph0 + 16 * 512;
    const unsigned short* pb0 = Wg + (size_t)(g * 512 + d0 + lm) * 3072 + lk;
    const unsigned short* pb1 = pb0 + (size_t)16 * 3072;
    f32x4 acc00 = {0.f, 0.f, 0.f, 0.f}, acc01 = acc00, acc10 = acc00, acc11 = acc00;
    int k0 = ks * 768;
    #pragma unroll 4
    for (int kk = 0; kk < 768; kk += 32) {
        int k = k0 + kk;
        bf16x8 a0, a1;
        if (k < 512)       { a0 = *(const bf16x8*)(pe0 + k);
                             a1 = *(const bf16x8*)(pe1 + k); }
        else if (k < 2560) { a0 = *(const bf16x8*)(pw0 + (k - 512));
                             a1 = *(const bf16x8*)(pw1 + (k - 512)); }
        else               { a0 = *(const bf16x8*)(ph0 + (k - 2560));
                             a1 = *(const bf16x8*)(ph1 + (k - 2560)); }
        bf16x8 b0 = *(const bf16x8*)(pb0 + k);
        bf16x8 b1 = *(const bf16x8*)(pb1 + k);
        acc00 = __builtin_amdgcn_mfma_f32_16x16x32_bf16(a0, b0, acc00, 0, 0, 0);
        acc01 = __builtin_amdgcn_mfma_f32_16x16x32_bf16(a0, b1, acc01, 0, 0, 0);
        acc10 = __builtin_amdgcn_mfma_f32_16x16x32_bf16(a1, b0, acc10, 0, 0, 0);
        acc11 = __builtin_amdgcn_mfma_f32_16x16x32_bf16(a1, b1, acc11, 0, 0, 0);
    }
    int orow = (l >> 4) << 2;
    if (ks > 0) {
        int slot = (ks - 1) * 4 + g;
        #pragma unroll
        for (int mi = 0; mi < 2; ++mi)
            #pragma unroll
            for (int ni = 0; ni < 2; ++ni) {
                f32x4 v = (mi == 0) ? (ni == 0 ? acc00 : acc01)
                                    : (ni == 0 ? acc10 : acc11);
                #pragma unroll
                for (int r = 0; r < 4; ++r)
                    red[slot][(mi * 16 + orow + r) * 32 + ni * 16 + lm] = v[r];
            }
    }
    __syncthreads();
    if (ks == 0) {
        #pragma unroll
        for (int mi = 0; mi < 2; ++mi)
            #pragma unroll
            for (int ni = 0; ni < 2; ++ni) {
                f32x4 v = (mi == 0) ? (ni == 0 ? acc00 : acc01)
                                    : (ni == 0 ? acc10 : acc11);
                #pragma unroll
                for (int r = 0; r < 4; ++r) {
                    int idx = (mi * 16 + orow + r) * 32 + ni * 16 + lm;
                    gates[g][idx] = v[r] + red[g][idx] + red[4 + g][idx] + red[8 + g][idx];
                }
            }
    }
    __syncthreads();
    {
        int row = tid >> 5, d = tid & 31;
        int R = row0 + row, D = d0 + d;
        int e = row * 32 + d;
        float gi = gates[0][e] + bsum[D];
        float gf = gates[1][e] + bsum[512 + D];
        float gg = gates[2][e] + bsum[1024 + D];
        float go = gates[3][e] + bsum[1536 + D];
        size_t idx = (size_t)R * 512 + D;
        float cn = sigf(gf) * c[idx] + sigf(gi) * tanhf(gg);
        float hn = sigf(go) * tanhf(cn);
        hnew16[idx] = f2bf(hn);
        if (t < dec_len[R]) {
            c[idx] = cn;
            h16out[idx] = f2bf(hn);
        }
    }
}

// ---------------------------------------------------------------------------
// Batched fc: out[(b*31+t)*10000+col] = mask * (hnew_all[t*128+b] @ Wfc^T + b_fc)
// 64x64 tile, 4 waves (2x2 quadrants of 32x32). grid (157, 62), 256 threads.
// ---------------------------------------------------------------------------
__global__ __launch_bounds__(256) void fc_batched(
    const unsigned short* __restrict__ hnew_all,  // [31*128][512]
    const unsigned short* __restrict__ Wfc,
    const float* __restrict__ b_fc,
    const int* __restrict__ dec_len,
    float* __restrict__ out) {
    int tid = threadIdx.x;
    int w = tid >> 6, l = tid & 63;
    int mi2 = w >> 1, ni2 = w & 1;
    int lm = l & 15, lk = ((l >> 4) << 3);
    int row0 = blockIdx.y * 64 + mi2 * 32;
    int col0 = blockIdx.x * 64 + ni2 * 32;
    const unsigned short* pa0 = hnew_all + (size_t)(row0 + lm) * 512 + lk;
    const unsigned short* pa1 = pa0 + 16 * 512;
    int bn0 = col0 + lm; if (bn0 > 9999) bn0 = 9999;
    int bn1 = col0 + 16 + lm; if (bn1 > 9999) bn1 = 9999;
    const unsigned short* pb0 = Wfc + (size_t)bn0 * 512 + lk;
    const unsigned short* pb1 = Wfc + (size_t)bn1 * 512 + lk;
    f32x4 acc00 = {0.f, 0.f, 0.f, 0.f}, acc01 = acc00, acc10 = acc00, acc11 = acc00;
    #pragma unroll 4
    for (int k = 0; k < 512; k += 32) {
        bf16x8 a0 = *(const bf16x8*)(pa0 + k);
        bf16x8 a1 = *(const bf16x8*)(pa1 + k);
        bf16x8 b0 = *(const bf16x8*)(pb0 + k);
        bf16x8 b1 = *(const bf16x8*)(pb1 + k);
        acc00 = __builtin_amdgcn_mfma_f32_16x16x32_bf16(a0, b0, acc00, 0, 0, 0);
        acc01 = __builtin_amdgcn_mfma_f32_16x16x32_bf16(a0, b1, acc01, 0, 0, 0);
        acc10 = __builtin_amdgcn_mfma_f32_16x16x32_bf16(a1, b0, acc10, 0, 0, 0);
        acc11 = __builtin_amdgcn_mfma_f32_16x16x32_bf16(a1, b1, acc11, 0, 0, 0);
    }
    int orow = (l >> 4) << 2;
    #pragma unroll
    for (int mi = 0; mi < 2; ++mi)
        #pragma unroll
        for (int ni = 0; ni < 2; ++ni) {
            f32x4 v = (mi == 0) ? (ni == 0 ? acc00 : acc01)
                                : (ni == 0 ? acc10 : acc11);
            int col = col0 + ni * 16 + lm;
            if (col >= 10000) continue;
            #pragma unroll
            for (int r = 0; r < 4; ++r) {
                int row = row0 + mi * 16 + orow + r;
                int t = row >> 7, b = row & 127;
                float val = v[r] + b_fc[col];
                bool m = t < dec_len[b];
                out[OFF_PRED + ((size_t)b * 31 + t) * 10000 + col] = m ? val : 0.0f;
            }
        }
}

// ---------------------------------------------------------------------------
__global__ void alphas_kernel(const int* __restrict__ dec_len,
                              float* __restrict__ dout) {
    int idx = blockIdx.x * 256 + threadIdx.x;  // 777728
    int b = idx / (31 * 196);
    int r = idx % (31 * 196);
    int t = r / 196;
    dout[OFF_ALPHA + idx] = (t < dec_len[b]) ? (1.0f / 196.0f) : 0.0f;
}

// ---------------------------------------------------------------------------
static inline char* align256(char* p) {
    return (char*)(((uintptr_t)p + 255) & ~(uintptr_t)255);
}

extern "C" void kernel_launch(void* const* d_in, const int* in_sizes, int n_in,
                              void* d_out, int out_size, void* d_ws, size_t ws_size,
                              hipStream_t stream) {
    const float* enc_feature  = (const float*)d_in[0];
    const int*   enc_capt     = (const int*)d_in[1];
    const int*   capt_lengths = (const int*)d_in[2];
    const float* emb     = (const float*)d_in[3];
    const float* W_ih    = (const float*)d_in[4];
    const float* b_ih    = (const float*)d_in[5];
    const float* W_hh    = (const float*)d_in[6];
    const float* b_hh    = (const float*)d_in[7];
    const float* W_inith = (const float*)d_in[8];
    const float* b_inith = (const float*)d_in[9];
    const float* W_initc = (const float*)d_in[10];
    const float* b_initc = (const float*)d_in[11];
    const float* W_fbeta = (const float*)d_in[12];
    const float* b_fbeta = (const float*)d_in[13];
    const float* W_fc    = (const float*)d_in[14];
    const float* b_fc    = (const float*)d_in[15];
    float* out = (float*)d_out;

    char* ws = (char*)d_ws;
    int* sort_ind    = (int*)ws;  ws += 512;
    int* dec_len     = (int*)ws;  ws += 512;
    int* capt_sorted = (int*)ws;  ws += 128 * MAXLEN * sizeof(int);
    ws = align256(ws);
    float* mean_feat = (float*)ws; ws += (size_t)128 * 2048 * 4;
    float* c         = (float*)ws; ws += (size_t)128 * 512 * 4;
    float* bsum      = (float*)ws; ws += 2048 * 4;
    unsigned short* mean16   = (unsigned short*)ws; ws += (size_t)128 * 2048 * 2;
    unsigned short* h16      = (unsigned short*)ws; ws += (size_t)128 * 512 * 2;
    unsigned short* awe16    = (unsigned short*)ws; ws += (size_t)128 * 2048 * 2;
    unsigned short* Wfb16    = (unsigned short*)ws; ws += (size_t)2048 * 512 * 2;
    unsigned short* Wg16     = (unsigned short*)ws; ws += (size_t)2048 * 3072 * 2;
    unsigned short* Wfc16    = (unsigned short*)ws; ws += (size_t)10000 * 512 * 2;
    unsigned short* Winith16 = (unsigned short*)ws; ws += (size_t)512 * 2048 * 2;
    unsigned short* Winitc16 = (unsigned short*)ws; ws += (size_t)512 * 2048 * 2;
    unsigned short* embs16   = (unsigned short*)ws; ws += (size_t)31 * 128 * 512 * 2;
    unsigned short* hnew_all = (unsigned short*)ws; ws += (size_t)31 * 128 * 512 * 2;

    sort_kernel<<<1, 128, 0, stream>>>(capt_lengths, enc_capt, sort_ind, dec_len,
                                       capt_sorted, out);
    mean_kernel<<<dim3(8, 128), 256, 0, stream>>>(enc_feature, sort_ind,
                                                  mean_feat, mean16);

    f32_to_bf16<<<(2048 * 512 / 4 + 255) / 256, 256, 0, stream>>>(W_fbeta, Wfb16, 2048 * 512);
    f32_to_bf16<<<(10000 * 512 / 4 + 255) / 256, 256, 0, stream>>>(W_fc, Wfc16, 10000 * 512);
    f32_to_bf16<<<(512 * 2048 / 4 + 255) / 256, 256, 0, stream>>>(W_inith, Winith16, 512 * 2048);
    f32_to_bf16<<<(512 * 2048 / 4 + 255) / 256, 256, 0, stream>>>(W_initc, Winitc16, 512 * 2048);
    concat_wg<<<dim3(12, 2048), 256, 0, stream>>>(W_ih, W_hh, Wg16);
    bsum_kernel<<<8, 256, 0, stream>>>(b_ih, b_hh, bsum);
    embs_gather<<<(31 * 128 * 512 + 255) / 256, 256, 0, stream>>>(emb, capt_sorted, embs16);

    // h0 (bf16) and c0 (fp32)
    mfma_gemm<4><<<dim3(16, 4), 64, 0, stream>>>(
        mean16, 2048, Winith16, 2048, 512, 2048, b_inith, nullptr, h16, 512);
    mfma_gemm<0><<<dim3(16, 4), 64, 0, stream>>>(
        mean16, 2048, Winitc16, 2048, 512, 2048, b_initc, c, nullptr, 512);

    for (int t = 0; t < T_STEPS; ++t) {
        awe_fused<<<dim3(32, 4), 256, 0, stream>>>(
            h16, Wfb16, b_fbeta, mean_feat, awe16);
        lstm_fused<<<dim3(16, 4), 1024, 0, stream>>>(
            embs16 + (size_t)t * 128 * 512, awe16, h16, Wg16, bsum,
            c, h16, hnew_all + (size_t)t * 128 * 512, dec_len, t);
    }

    fc_batched<<<dim3(157, 62), 256, 0, stream>>>(
        hnew_all, Wfc16, b_fc, dec_len, out);
    alphas_kernel<<<3038, 256, 0, stream>>>(dec_len, out);
}

// Round 5
// 1906.987 us; speedup vs baseline: 1.2274x; 1.2274x over previous
//
#include <hip/hip_runtime.h>
#include <hip/hip_bf16.h>
#include <math.h>

// Problem constants
#define NB       128
#define P_HW     196
#define ENC_C    2048
#define V_SZ     10000
#define E_SZ     512
#define D_SZ     512
#define MAXLEN   32
#define T_STEPS  31

// d_out layout (floats), in reference return order
#define SZ_PRED    (128ULL * 31ULL * 10000ULL)
#define OFF_PRED   0ULL
#define OFF_CAPT   (SZ_PRED)
#define OFF_DECLEN (OFF_CAPT + 128ULL * 32ULL)
#define OFF_ALPHA  (OFF_DECLEN + 128ULL)
#define OFF_SORT   (OFF_ALPHA + 128ULL * 31ULL * 196ULL)

typedef __bf16 bf16x8 __attribute__((ext_vector_type(8)));
typedef float f32x4 __attribute__((ext_vector_type(4)));

__device__ __forceinline__ float sigf(float x) { return 1.0f / (1.0f + __expf(-x)); }

__device__ __forceinline__ unsigned short f2bf(float f) {
    unsigned int u = __float_as_uint(f);
    unsigned int r = (u + 0x7fffu + ((u >> 16) & 1u)) >> 16;  // RNE
    return (unsigned short)r;
}

// ---------------------------------------------------------------------------
// Stable descending sort by caption length (rank via O(N^2) count)
// ---------------------------------------------------------------------------
__global__ void sort_kernel(const int* __restrict__ capt_lengths,
                            const int* __restrict__ enc_capt,
                            int* __restrict__ sort_ind_ws,
                            int* __restrict__ dec_len_ws,
                            int* __restrict__ capt_sorted_ws,
                            float* __restrict__ dout) {
    __shared__ int cl[NB];
    int i = threadIdx.x;
    cl[i] = capt_lengths[i];
    __syncthreads();
    int my = cl[i];
    int rank = 0;
    #pragma unroll 4
    for (int j = 0; j < NB; ++j) {
        int cj = cl[j];
        rank += (cj > my) || (cj == my && j < i);
    }
    sort_ind_ws[rank] = i;
    dec_len_ws[rank]  = my - 1;
    dout[OFF_SORT + rank]   = (float)i;
    dout[OFF_DECLEN + rank] = (float)(my - 1);
    for (int t = 0; t < MAXLEN; ++t) {
        int tok = enc_capt[i * MAXLEN + t];
        capt_sorted_ws[rank * MAXLEN + t] = tok;
        dout[OFF_CAPT + rank * MAXLEN + t] = (float)tok;
    }
}

// ---------------------------------------------------------------------------
// mean_feat[b, e] = mean over 196 positions; writes fp32 + bf16 copies
// ---------------------------------------------------------------------------
__global__ void mean_kernel(const float* __restrict__ enc_feature,
                            const int* __restrict__ sort_ind,
                            float* __restrict__ mean_feat,
                            unsigned short* __restrict__ mean16) {
    int b = blockIdx.y;
    int e = blockIdx.x * 256 + threadIdx.x;
    int src = sort_ind[b];
    const float* base = enc_feature + (size_t)src * P_HW * ENC_C + e;
    float s = 0.0f;
    #pragma unroll 4
    for (int p = 0; p < P_HW; ++p) s += base[(size_t)p * ENC_C];
    float m = s * (1.0f / (float)P_HW);
    mean_feat[(size_t)b * ENC_C + e] = m;
    mean16[(size_t)b * ENC_C + e] = f2bf(m);
}

// ---------------------------------------------------------------------------
__global__ void f32_to_bf16(const float* __restrict__ src,
                            unsigned short* __restrict__ dst, int n) {
    int i = (blockIdx.x * 256 + threadIdx.x) * 4;
    if (i < n) {
        float4 v = *reinterpret_cast<const float4*>(src + i);
        dst[i + 0] = f2bf(v.x);
        dst[i + 1] = f2bf(v.y);
        dst[i + 2] = f2bf(v.z);
        dst[i + 3] = f2bf(v.w);
    }
}

// Wg16[n][0:2560] = W_ih[n], Wg16[n][2560:3072] = W_hh[n]
__global__ void concat_wg(const float* __restrict__ W_ih,
                          const float* __restrict__ W_hh,
                          unsigned short* __restrict__ Wg16) {
    int n = blockIdx.y;
    int col = blockIdx.x * 256 + threadIdx.x;  // < 3072
    float v = (col < 2560) ? W_ih[(size_t)n * 2560 + col]
                           : W_hh[(size_t)n * 512 + (col - 2560)];
    Wg16[(size_t)n * 3072 + col] = f2bf(v);
}

__global__ void bsum_kernel(const float* __restrict__ b_ih,
                            const float* __restrict__ b_hh,
                            float* __restrict__ bsum) {
    int i = blockIdx.x * 256 + threadIdx.x;  // 2048
    bsum[i] = b_ih[i] + b_hh[i];
}

// embs16[t][b][e] = bf16(emb[capt_sorted[b][t]][e])
__global__ void embs_gather(const float* __restrict__ emb,
                            const int* __restrict__ capt_sorted,
                            unsigned short* __restrict__ embs16) {
    int idx = blockIdx.x * 256 + threadIdx.x;  // 31*128*512
    if (idx >= 31 * 128 * 512) return;
    int t = idx >> 16;
    int r = idx & 65535;
    int b = r >> 9;
    int tok = capt_sorted[b * MAXLEN + t];
    embs16[idx] = f2bf(emb[(size_t)tok * E_SZ + (r & 511)]);
}

// ---------------------------------------------------------------------------
// LDS-free 1-wave MFMA GEMM (used only for the two init GEMMs).
// EPI 0: Cf = acc + bias ; EPI 4: Cb = bf16(acc + bias)
// ---------------------------------------------------------------------------
template <int EPI>
__global__ __launch_bounds__(64) void mfma_gemm(
    const unsigned short* __restrict__ A, int lda,
    const unsigned short* __restrict__ B, int ldb,
    int Nout, int K,
    const float* __restrict__ bias,
    float* __restrict__ Cf, unsigned short* __restrict__ Cb, int ldc) {
    int l = threadIdx.x;
    int lm = l & 15;
    int lk = (l >> 4) << 3;
    int row0 = blockIdx.y << 5;
    int col0 = blockIdx.x << 5;
    const unsigned short* pa0 = A + (size_t)(row0 + lm) * lda + lk;
    const unsigned short* pa1 = pa0 + ((size_t)lda << 4);
    const unsigned short* pb0 = B + (size_t)(col0 + lm) * ldb + lk;
    const unsigned short* pb1 = pb0 + ((size_t)ldb << 4);
    f32x4 acc00 = {0.f, 0.f, 0.f, 0.f}, acc01 = acc00, acc10 = acc00, acc11 = acc00;
    for (int k = 0; k < K; k += 32) {
        bf16x8 a0 = *(const bf16x8*)(pa0 + k);
        bf16x8 a1 = *(const bf16x8*)(pa1 + k);
        bf16x8 b0 = *(const bf16x8*)(pb0 + k);
        bf16x8 b1 = *(const bf16x8*)(pb1 + k);
        acc00 = __builtin_amdgcn_mfma_f32_16x16x32_bf16(a0, b0, acc00, 0, 0, 0);
        acc01 = __builtin_amdgcn_mfma_f32_16x16x32_bf16(a0, b1, acc01, 0, 0, 0);
        acc10 = __builtin_amdgcn_mfma_f32_16x16x32_bf16(a1, b0, acc10, 0, 0, 0);
        acc11 = __builtin_amdgcn_mfma_f32_16x16x32_bf16(a1, b1, acc11, 0, 0, 0);
    }
    int orow = (l >> 4) << 2;
    #pragma unroll
    for (int mi = 0; mi < 2; ++mi) {
        #pragma unroll
        for (int ni = 0; ni < 2; ++ni) {
            f32x4 v = (mi == 0) ? (ni == 0 ? acc00 : acc01)
                                : (ni == 0 ? acc10 : acc11);
            int col = col0 + ni * 16 + lm;
            #pragma unroll
            for (int r = 0; r < 4; ++r) {
                int row = row0 + mi * 16 + orow + r;
                float val = v[r] + bias[col];
                if (EPI == 0) Cf[(size_t)row * ldc + col] = val;
                else          Cb[(size_t)row * ldc + col] = f2bf(val);
            }
        }
    }
}

// ---------------------------------------------------------------------------
// awe = bf16(mean * sigmoid(h @ Wfb^T + b)), 4 waves: 2 col-tiles x K-split-2
// grid (32, 4), 256 threads. Block: 32 rows x 64 cols.
// ---------------------------------------------------------------------------
__global__ __launch_bounds__(256) void awe_fused(
    const unsigned short* __restrict__ h16,
    const unsigned short* __restrict__ Wfb,
    const float* __restrict__ b_fbeta,
    const float* __restrict__ meanfeat,
    unsigned short* __restrict__ awe16) {
    __shared__ float red[2][1024];
    int tid = threadIdx.x;
    int w = tid >> 6, l = tid & 63;
    int ct = w >> 1, ks = w & 1;
    int lm = l & 15, lk = ((l >> 4) << 3);
    int row0 = blockIdx.y << 5;
    int col0 = (blockIdx.x << 6) + (ct << 5);
    int kbase = ks << 8;  // 0 or 256
    const unsigned short* pa0 = h16 + (size_t)(row0 + lm) * 512 + kbase + lk;
    const unsigned short* pa1 = pa0 + 16 * 512;
    const unsigned short* pb0 = Wfb + (size_t)(col0 + lm) * 512 + kbase + lk;
    const unsigned short* pb1 = pb0 + 16 * 512;
    f32x4 acc00 = {0.f, 0.f, 0.f, 0.f}, acc01 = acc00, acc10 = acc00, acc11 = acc00;
    #pragma unroll
    for (int k = 0; k < 256; k += 32) {
        bf16x8 a0 = *(const bf16x8*)(pa0 + k);
        bf16x8 a1 = *(const bf16x8*)(pa1 + k);
        bf16x8 b0 = *(const bf16x8*)(pb0 + k);
        bf16x8 b1 = *(const bf16x8*)(pb1 + k);
        acc00 = __builtin_amdgcn_mfma_f32_16x16x32_bf16(a0, b0, acc00, 0, 0, 0);
        acc01 = __builtin_amdgcn_mfma_f32_16x16x32_bf16(a0, b1, acc01, 0, 0, 0);
        acc10 = __builtin_amdgcn_mfma_f32_16x16x32_bf16(a1, b0, acc10, 0, 0, 0);
        acc11 = __builtin_amdgcn_mfma_f32_16x16x32_bf16(a1, b1, acc11, 0, 0, 0);
    }
    int orow = (l >> 4) << 2;
    if (ks == 1) {
        #pragma unroll
        for (int mi = 0; mi < 2; ++mi)
            #pragma unroll
            for (int ni = 0; ni < 2; ++ni) {
                f32x4 v = (mi == 0) ? (ni == 0 ? acc00 : acc01)
                                    : (ni == 0 ? acc10 : acc11);
                #pragma unroll
                for (int r = 0; r < 4; ++r)
                    red[ct][(mi * 16 + orow + r) * 32 + ni * 16 + lm] = v[r];
            }
    }
    __syncthreads();
    if (ks == 0) {
        #pragma unroll
        for (int mi = 0; mi < 2; ++mi)
            #pragma unroll
            for (int ni = 0; ni < 2; ++ni) {
                f32x4 v = (mi == 0) ? (ni == 0 ? acc00 : acc01)
                                    : (ni == 0 ? acc10 : acc11);
                int col = col0 + ni * 16 + lm;
                #pragma unroll
                for (int r = 0; r < 4; ++r) {
                    int row = row0 + mi * 16 + orow + r;
                    float val = v[r] + red[ct][(mi * 16 + orow + r) * 32 + ni * 16 + lm]
                              + b_fbeta[col];
                    awe16[(size_t)row * 2048 + col] =
                        f2bf(meanfeat[(size_t)row * 2048 + col] * sigf(val));
                }
            }
    }
}

// ---------------------------------------------------------------------------
// Fused LSTM gate GEMM + pointwise, v2.
// Block: 32 rows x 16 d-cols (x4 gates = 64 Wg rows). 16 waves = 4 gates x
// K-split-4 (768 each). grid (32, 4), 1024 threads. h ping-pong (race-free).
// ---------------------------------------------------------------------------
__global__ __launch_bounds__(1024) void lstm_fused2(
    const unsigned short* __restrict__ embt,   // 128 x 512 (this step)
    const unsigned short* __restrict__ awe16,  // 128 x 2048
    const unsigned short* __restrict__ h_in,   // 128 x 512
    const unsigned short* __restrict__ Wg,     // 2048 x 3072
    const float* __restrict__ bsum,
    float* __restrict__ c,
    unsigned short* __restrict__ h_out,        // ping-pong partner
    unsigned short* __restrict__ hnew16,       // hnew_all + t*65536
    const int* __restrict__ dec_len, int t) {
    __shared__ float red[12][512];
    int tid = threadIdx.x;
    int w = tid >> 6, l = tid & 63;
    int g = w & 3, ks = w >> 2;       // gate, K-split index
    int lm = l & 15, lk = ((l >> 4) << 3);
    int r0 = blockIdx.y << 5;          // 32-row block
    int d0 = blockIdx.x << 4;          // 16 d-cols
    int ra = r0 + lm;
    const unsigned short* pe0 = embt  + (size_t)ra * 512  + lk;
    const unsigned short* pe1 = pe0 + 16 * 512;
    const unsigned short* pw0 = awe16 + (size_t)ra * 2048 + lk;
    const unsigned short* pw1 = pw0 + 16 * 2048;
    const unsigned short* ph0 = h_in  + (size_t)ra * 512  + lk;
    const unsigned short* ph1 = ph0 + 16 * 512;
    const unsigned short* pb  = Wg + (size_t)(g * 512 + d0 + lm) * 3072 + lk;
    f32x4 acc0 = {0.f, 0.f, 0.f, 0.f}, acc1 = acc0;
    int k0 = ks * 768;
    #pragma unroll 8
    for (int kk = 0; kk < 768; kk += 32) {
        int k = k0 + kk;
        bf16x8 a0, a1;
        if (k < 512)       { a0 = *(const bf16x8*)(pe0 + k);
                             a1 = *(const bf16x8*)(pe1 + k); }
        else if (k < 2560) { a0 = *(const bf16x8*)(pw0 + (k - 512));
                             a1 = *(const bf16x8*)(pw1 + (k - 512)); }
        else               { a0 = *(const bf16x8*)(ph0 + (k - 2560));
                             a1 = *(const bf16x8*)(ph1 + (k - 2560)); }
        bf16x8 b = *(const bf16x8*)(pb + k);
        acc0 = __builtin_amdgcn_mfma_f32_16x16x32_bf16(a0, b, acc0, 0, 0, 0);
        acc1 = __builtin_amdgcn_mfma_f32_16x16x32_bf16(a1, b, acc1, 0, 0, 0);
    }
    int orow = (l >> 4) << 2;
    if (ks > 0) {
        int slot = (ks - 1) * 4 + g;
        #pragma unroll
        for (int r = 0; r < 4; ++r) {
            red[slot][(orow + r) * 16 + lm]      = acc0[r];
            red[slot][(16 + orow + r) * 16 + lm] = acc1[r];
        }
    }
    __syncthreads();
    if (ks == 0) {
        #pragma unroll
        for (int r = 0; r < 4; ++r) {
            int e0 = (orow + r) * 16 + lm;
            int e1 = (16 + orow + r) * 16 + lm;
            red[g][e0] = acc0[r] + red[g][e0] + red[4 + g][e0] + red[8 + g][e0];
            red[g][e1] = acc1[r] + red[g][e1] + red[4 + g][e1] + red[8 + g][e1];
        }
    }
    __syncthreads();
    if (tid < 512) {
        int r = tid >> 4, d = tid & 15;
        int R = r0 + r, D = d0 + d;
        int e = r * 16 + d;
        float gi = red[0][e] + bsum[D];
        float gf = red[1][e] + bsum[512 + D];
        float gg = red[2][e] + bsum[1024 + D];
        float go = red[3][e] + bsum[1536 + D];
        size_t idx = (size_t)R * 512 + D;
        float cn = sigf(gf) * c[idx] + sigf(gi) * tanhf(gg);
        float hn = sigf(go) * tanhf(cn);
        unsigned short hb = f2bf(hn);
        hnew16[idx] = hb;
        if (t < dec_len[R]) {
            c[idx] = cn;
            h_out[idx] = hb;
        } else {
            h_out[idx] = h_in[idx];
        }
    }
}

// ---------------------------------------------------------------------------
// Batched fc: 128x128 tiles, 4 waves (2x2 of 64x64, 4x4 frags).
// grid (31 M-tiles FAST, 79 N-tiles) so in-flight blocks share one Wfc panel
// and hnew_all (4MB) stays L2-resident.
// ---------------------------------------------------------------------------
__global__ __launch_bounds__(256) void fc128(
    const unsigned short* __restrict__ hnew_all,  // [3968][512]
    const unsigned short* __restrict__ Wfc,
    const float* __restrict__ b_fc,
    const int* __restrict__ dec_len,
    float* __restrict__ out) {
    int tid = threadIdx.x;
    int w = tid >> 6, l = tid & 63;
    int wm = w >> 1, wn = w & 1;
    int lm = l & 15, lk = ((l >> 4) << 3);
    int row0 = blockIdx.x * 128 + wm * 64;
    int col0 = blockIdx.y * 128 + wn * 64;
    const unsigned short* pa[4];
    const unsigned short* pb[4];
    #pragma unroll
    for (int i = 0; i < 4; ++i) {
        pa[i] = hnew_all + (size_t)(row0 + i * 16 + lm) * 512 + lk;
        int bn = col0 + i * 16 + lm; if (bn > 9999) bn = 9999;
        pb[i] = Wfc + (size_t)bn * 512 + lk;
    }
    f32x4 acc[4][4];
    #pragma unroll
    for (int i = 0; i < 4; ++i)
        #pragma unroll
        for (int j = 0; j < 4; ++j) acc[i][j] = (f32x4){0.f, 0.f, 0.f, 0.f};
    for (int k = 0; k < 512; k += 32) {
        bf16x8 a[4], b[4];
        #pragma unroll
        for (int i = 0; i < 4; ++i) a[i] = *(const bf16x8*)(pa[i] + k);
        #pragma unroll
        for (int j = 0; j < 4; ++j) b[j] = *(const bf16x8*)(pb[j] + k);
        #pragma unroll
        for (int i = 0; i < 4; ++i)
            #pragma unroll
            for (int j = 0; j < 4; ++j)
                acc[i][j] = __builtin_amdgcn_mfma_f32_16x16x32_bf16(a[i], b[j], acc[i][j], 0, 0, 0);
    }
    int orow = (l >> 4) << 2;
    #pragma unroll
    for (int i = 0; i < 4; ++i) {
        #pragma unroll
        for (int j = 0; j < 4; ++j) {
            int col = col0 + j * 16 + lm;
            if (col >= 10000) continue;
            float bias = b_fc[col];
            #pragma unroll
            for (int r = 0; r < 4; ++r) {
                int row = row0 + i * 16 + orow + r;
                int t = row >> 7, b = row & 127;
                bool m = t < dec_len[b];
                out[OFF_PRED + ((size_t)b * 31 + t) * 10000 + col] =
                    m ? (acc[i][j][r] + bias) : 0.0f;
            }
        }
    }
}

// ---------------------------------------------------------------------------
__global__ void alphas_kernel(const int* __restrict__ dec_len,
                              float* __restrict__ dout) {
    int idx = blockIdx.x * 256 + threadIdx.x;  // 777728
    int b = idx / (31 * 196);
    int r = idx % (31 * 196);
    int t = r / 196;
    dout[OFF_ALPHA + idx] = (t < dec_len[b]) ? (1.0f / 196.0f) : 0.0f;
}

// ---------------------------------------------------------------------------
static inline char* align256(char* p) {
    return (char*)(((uintptr_t)p + 255) & ~(uintptr_t)255);
}

extern "C" void kernel_launch(void* const* d_in, const int* in_sizes, int n_in,
                              void* d_out, int out_size, void* d_ws, size_t ws_size,
                              hipStream_t stream) {
    const float* enc_feature  = (const float*)d_in[0];
    const int*   enc_capt     = (const int*)d_in[1];
    const int*   capt_lengths = (const int*)d_in[2];
    const float* emb     = (const float*)d_in[3];
    const float* W_ih    = (const float*)d_in[4];
    const float* b_ih    = (const float*)d_in[5];
    const float* W_hh    = (const float*)d_in[6];
    const float* b_hh    = (const float*)d_in[7];
    const float* W_inith = (const float*)d_in[8];
    const float* b_inith = (const float*)d_in[9];
    const float* W_initc = (const float*)d_in[10];
    const float* b_initc = (const float*)d_in[11];
    const float* W_fbeta = (const float*)d_in[12];
    const float* b_fbeta = (const float*)d_in[13];
    const float* W_fc    = (const float*)d_in[14];
    const float* b_fc    = (const float*)d_in[15];
    float* out = (float*)d_out;

    char* ws = (char*)d_ws;
    int* sort_ind    = (int*)ws;  ws += 512;
    int* dec_len     = (int*)ws;  ws += 512;
    int* capt_sorted = (int*)ws;  ws += 128 * MAXLEN * sizeof(int);
    ws = align256(ws);
    float* mean_feat = (float*)ws; ws += (size_t)128 * 2048 * 4;
    float* c         = (float*)ws; ws += (size_t)128 * 512 * 4;
    float* bsum      = (float*)ws; ws += 2048 * 4;
    unsigned short* mean16   = (unsigned short*)ws; ws += (size_t)128 * 2048 * 2;
    unsigned short* hbuf0    = (unsigned short*)ws; ws += (size_t)128 * 512 * 2;
    unsigned short* hbuf1    = (unsigned short*)ws; ws += (size_t)128 * 512 * 2;
    unsigned short* awe16    = (unsigned short*)ws; ws += (size_t)128 * 2048 * 2;
    unsigned short* Wfb16    = (unsigned short*)ws; ws += (size_t)2048 * 512 * 2;
    unsigned short* Wg16     = (unsigned short*)ws; ws += (size_t)2048 * 3072 * 2;
    unsigned short* Wfc16    = (unsigned short*)ws; ws += (size_t)10000 * 512 * 2;
    unsigned short* Winith16 = (unsigned short*)ws; ws += (size_t)512 * 2048 * 2;
    unsigned short* Winitc16 = (unsigned short*)ws; ws += (size_t)512 * 2048 * 2;
    unsigned short* embs16   = (unsigned short*)ws; ws += (size_t)31 * 128 * 512 * 2;
    unsigned short* hnew_all = (unsigned short*)ws; ws += (size_t)31 * 128 * 512 * 2;

    sort_kernel<<<1, 128, 0, stream>>>(capt_lengths, enc_capt, sort_ind, dec_len,
                                       capt_sorted, out);
    mean_kernel<<<dim3(8, 128), 256, 0, stream>>>(enc_feature, sort_ind,
                                                  mean_feat, mean16);

    f32_to_bf16<<<(2048 * 512 / 4 + 255) / 256, 256, 0, stream>>>(W_fbeta, Wfb16, 2048 * 512);
    f32_to_bf16<<<(10000 * 512 / 4 + 255) / 256, 256, 0, stream>>>(W_fc, Wfc16, 10000 * 512);
    f32_to_bf16<<<(512 * 2048 / 4 + 255) / 256, 256, 0, stream>>>(W_inith, Winith16, 512 * 2048);
    f32_to_bf16<<<(512 * 2048 / 4 + 255) / 256, 256, 0, stream>>>(W_initc, Winitc16, 512 * 2048);
    concat_wg<<<dim3(12, 2048), 256, 0, stream>>>(W_ih, W_hh, Wg16);
    bsum_kernel<<<8, 256, 0, stream>>>(b_ih, b_hh, bsum);
    embs_gather<<<(31 * 128 * 512 + 255) / 256, 256, 0, stream>>>(emb, capt_sorted, embs16);

    // h0 (bf16, into hbuf0) and c0 (fp32)
    mfma_gemm<4><<<dim3(16, 4), 64, 0, stream>>>(
        mean16, 2048, Winith16, 2048, 512, 2048, b_inith, nullptr, hbuf0, 512);
    mfma_gemm<0><<<dim3(16, 4), 64, 0, stream>>>(
        mean16, 2048, Winitc16, 2048, 512, 2048, b_initc, c, nullptr, 512);

    unsigned short* hb[2] = {hbuf0, hbuf1};
    for (int t = 0; t < T_STEPS; ++t) {
        unsigned short* hin  = hb[t & 1];
        unsigned short* hout = hb[(t + 1) & 1];
        awe_fused<<<dim3(32, 4), 256, 0, stream>>>(
            hin, Wfb16, b_fbeta, mean_feat, awe16);
        lstm_fused2<<<dim3(32, 4), 1024, 0, stream>>>(
            embs16 + (size_t)t * 128 * 512, awe16, hin, Wg16, bsum,
            c, hout, hnew_all + (size_t)t * 128 * 512, dec_len, t);
    }

    fc128<<<dim3(31, 79), 256, 0, stream>>>(
        hnew_all, Wfc16, b_fc, dec_len, out);
    alphas_kernel<<<3038, 256, 0, stream>>>(dec_len, out);
}